// Round 1
// 950.380 us; speedup vs baseline: 1.0043x; 1.0043x over previous
//
#include <hip/hip_runtime.h>
#include <hip/hip_bf16.h>
#include <math.h>

// Problem constants
#define B_  16
#define LP_ 512
#define LA_ 32
#define DP_ 1024
#define DA_ 512
#define HH_ 512
#define DO_ 1024

typedef unsigned short ushort_t;
typedef __attribute__((ext_vector_type(8))) short bf16x8;
typedef __attribute__((ext_vector_type(4))) float f32x4;

// Dtype helpers: MODE 0 = bf16 storage, MODE 1 = f32 storage.
__device__ __forceinline__ float toF(float x){ return x; }
__device__ __forceinline__ float toF(__hip_bfloat16 x){ return __bfloat162float(x); }
__device__ __forceinline__ void stT(float* p, float v){ *p = v; }
__device__ __forceinline__ void stT(__hip_bfloat16* p, float v){ *p = __float2bfloat16(v); }

// ---------------- dtype detector ----------------
__global__ void detect_mode(const unsigned short* __restrict__ raw,
                            int* __restrict__ flag) {
    __shared__ int cnt;
    if (threadIdx.x == 0) cnt = 0;
    __syncthreads();
    int e = (raw[threadIdx.x] >> 7) & 0xFF;
    if (e >= 160) atomicAdd(&cnt, 1);
    __syncthreads();
    if (threadIdx.x == 0) *flag = (cnt > 0) ? 1 : 0;
}

// ---------------- bf16 transpose: src[R][C] -> dst[C][R] (MODE 0 only) ----
__global__ __launch_bounds__(256) void transpose_bf16(
    const int* __restrict__ flag,
    const ushort_t* __restrict__ src, ushort_t* __restrict__ dst,
    int R, int C)
{
    if (*flag != 0) return;
    __shared__ ushort_t tile[32][33];
    const int nbx = C / 32;
    const int bx = blockIdx.x % nbx;   // C tile
    const int by = blockIdx.x / nbx;   // R tile
    const int tx = threadIdx.x % 32, ty = threadIdx.x / 32;  // 32x8
    const int c0 = bx * 32, r0 = by * 32;
#pragma unroll
    for (int i = ty; i < 32; i += 8)
        tile[i][tx] = src[(size_t)(r0 + i) * C + c0 + tx];
    __syncthreads();
#pragma unroll
    for (int i = ty; i < 32; i += 8)
        dst[(size_t)(c0 + i) * R + r0 + tx] = tile[tx][i];
}

// ---------------- MFMA bf16 GEMM ----------------
// C[M,N] = A[M,K] @ B[K,N] + bias, with B supplied TRANSPOSED as BT[N,K].
// 256 threads = 4 waves in 2x2; per-wave tile (BMt/2)x(BNt/2);
// 16x16x32 bf16 MFMA. A/B fragments both loaded with the SAME contiguous
// slot->k convention (k-permutation invariant for symmetric operands).
// CONCAT: A = [A0 (DP_ cols) | A1 (DA_ cols)]. OUTF32: f32 out else bf16.
template<int BMt, int BNt, int CONCAT, int RELU, int OUTF32>
__global__ __launch_bounds__(256) void gemm_mfma(
    const int* __restrict__ flag,
    const ushort_t* __restrict__ A0,
    const ushort_t* __restrict__ A1,
    const ushort_t* __restrict__ BT,
    const ushort_t* __restrict__ bias,
    void* __restrict__ Cout,
    int N, int K)
{
    if (*flag != 0) return;
    constexpr int SA = 40;              // 32 + 8 pad (keeps 16B align, 2-way banks)
    __shared__ ushort_t As[BMt * SA];
    __shared__ ushort_t Bs[BNt * SA];
    const int tid = threadIdx.x;
    const int nbx = N / BNt;
    const int colBase = (blockIdx.x % nbx) * BNt;
    const int rowBase = (blockIdx.x / nbx) * BMt;
    const int wid = tid >> 6, lane = tid & 63;
    const int wr = wid >> 1, wc = wid & 1;
    const int lrow = lane & 15;
    const int lk8 = (lane >> 4) * 8;    // contiguous 8-k slot base
    constexpr int FM = BMt / 32, FN = BNt / 32;

    f32x4 acc[FM][FN] = {};

    for (int k0 = 0; k0 < K; k0 += 32) {
        // stage A tile [BMt][32]
#pragma unroll
        for (int c = 0; c < BMt / 64; c++) {
            const int chunk = tid + c * 256;           // BMt*4 chunks of 8 bf16
            const int row = chunk >> 2, k8 = (chunk & 3) * 8;
            const int gk = k0 + k8;
            const ushort_t* ap;
            if (CONCAT) {
                ap = (gk < DP_) ? A0 + (size_t)(rowBase + row) * DP_ + gk
                                : A1 + (size_t)(rowBase + row) * DA_ + (gk - DP_);
            } else {
                ap = A0 + (size_t)(rowBase + row) * K + gk;
            }
            *(uint4*)&As[row * SA + k8] = *(const uint4*)ap;
        }
        // stage BT tile [BNt][32]
#pragma unroll
        for (int c = 0; c < BNt / 64; c++) {
            const int chunk = tid + c * 256;
            const int row = chunk >> 2, k8 = (chunk & 3) * 8;
            *(uint4*)&Bs[row * SA + k8] =
                *(const uint4*)(BT + (size_t)(colBase + row) * K + k0 + k8);
        }
        __syncthreads();

        bf16x8 af[FM], bfr[FN];
#pragma unroll
        for (int m = 0; m < FM; m++)
            af[m] = *(const bf16x8*)&As[(wr * (BMt / 2) + m * 16 + lrow) * SA + lk8];
#pragma unroll
        for (int n = 0; n < FN; n++)
            bfr[n] = *(const bf16x8*)&Bs[(wc * (BNt / 2) + n * 16 + lrow) * SA + lk8];
#pragma unroll
        for (int m = 0; m < FM; m++)
#pragma unroll
            for (int n = 0; n < FN; n++)
                acc[m][n] = __builtin_amdgcn_mfma_f32_16x16x32_bf16(
                    af[m], bfr[n], acc[m][n], 0, 0, 0);
        __syncthreads();
    }

    // epilogue: C/D layout col=lane&15, row=(lane>>4)*4+reg
#pragma unroll
    for (int n = 0; n < FN; n++) {
        const int gc = colBase + wc * (BNt / 2) + n * 16 + lrow;
        const float bv = __bfloat162float(*(const __hip_bfloat16*)&bias[gc]);
#pragma unroll
        for (int m = 0; m < FM; m++) {
            const int gr0 = rowBase + wr * (BMt / 2) + m * 16 + (lane >> 4) * 4;
#pragma unroll
            for (int r = 0; r < 4; r++) {
                float v = acc[m][n][r] + bv;
                if (RELU) v = v > 0.f ? v : 0.f;
                if (OUTF32)
                    ((float*)Cout)[(size_t)(gr0 + r) * N + gc] = v;
                else
                    ((__hip_bfloat16*)Cout)[(size_t)(gr0 + r) * N + gc] = __float2bfloat16(v);
            }
        }
    }
}

// ---------------- Legacy scalar GEMMs (f32 mode + ws-fallback) ----------------
#define BM 64
#define BN 64
#define BK 16

template<typename T, int MODE>
__global__ __launch_bounds__(256) void gemm_bias(
    const int* __restrict__ flag,
    const T* __restrict__ A,
    const T* __restrict__ Bm,
    const T* __restrict__ bias,
    float* __restrict__ C, int M, int N, int K)
{
    if (*flag != MODE) return;
    __shared__ float As[BK][BM + 1];
    __shared__ float Bs[BK][BN + 1];
    const int tid = threadIdx.x;
    const int nbx = N / BN;
    const int bx = blockIdx.x % nbx;
    const int by = blockIdx.x / nbx;
    const int rowBase = by * BM, colBase = bx * BN;
    const int ty = tid / 16, tx = tid % 16;
    float acc[4][4] = {};

    for (int k0 = 0; k0 < K; k0 += BK) {
        {
            const int am = tid >> 2, ak = (tid & 3) * 4;
            const T* ap = A + (size_t)(rowBase + am) * K + k0 + ak;
#pragma unroll
            for (int j = 0; j < 4; j++) As[ak + j][am] = toF(ap[j]);
        }
        {
            const int bk = tid >> 4, bn = (tid & 15) * 4;
            const T* bp2 = Bm + (size_t)(k0 + bk) * N + colBase + bn;
#pragma unroll
            for (int j = 0; j < 4; j++) Bs[bk][bn + j] = toF(bp2[j]);
        }
        __syncthreads();
#pragma unroll
        for (int kk = 0; kk < BK; kk++) {
            float ra[4], rb[4];
#pragma unroll
            for (int i = 0; i < 4; i++) ra[i] = As[kk][ty * 4 + i];
#pragma unroll
            for (int j = 0; j < 4; j++) rb[j] = Bs[kk][tx * 4 + j];
#pragma unroll
            for (int i = 0; i < 4; i++)
#pragma unroll
                for (int j = 0; j < 4; j++) acc[i][j] += ra[i] * rb[j];
        }
        __syncthreads();
    }
#pragma unroll
    for (int i = 0; i < 4; i++) {
        const int r = rowBase + ty * 4 + i;
#pragma unroll
        for (int j = 0; j < 4; j++) {
            const int c = colBase + tx * 4 + j;
            C[(size_t)r * N + c] = acc[i][j] + toF(bias[c]);
        }
    }
}

template<typename T, int MODE>
__global__ __launch_bounds__(256) void gemm_concat_relu(
    const int* __restrict__ flag,
    const T* __restrict__ A0,     // ppl [M, DP_]
    const T* __restrict__ A1,     // agg [M, DA_]
    const T* __restrict__ Bm,     // Wo [DP_+DA_, DO_]
    const T* __restrict__ bias,   // bo [DO_]
    T* __restrict__ Out, int M)
{
    if (*flag != MODE) return;
    const int N = DO_, K = DP_ + DA_;
    __shared__ float As[BK][BM + 1];
    __shared__ float Bs[BK][BN + 1];
    const int tid = threadIdx.x;
    const int nbx = N / BN;
    const int bx = blockIdx.x % nbx;
    const int by = blockIdx.x / nbx;
    const int rowBase = by * BM, colBase = bx * BN;
    const int ty = tid / 16, tx = tid % 16;
    float acc[4][4] = {};

    for (int k0 = 0; k0 < K; k0 += BK) {
        {
            const int am = tid >> 2, ak = (tid & 3) * 4;
            const int gk = k0 + ak;
            const T* ap = (gk < DP_)
                ? A0 + (size_t)(rowBase + am) * DP_ + gk
                : A1 + (size_t)(rowBase + am) * DA_ + (gk - DP_);
#pragma unroll
            for (int j = 0; j < 4; j++) As[ak + j][am] = toF(ap[j]);
        }
        {
            const int bk = tid >> 4, bn = (tid & 15) * 4;
            const T* bp2 = Bm + (size_t)(k0 + bk) * N + colBase + bn;
#pragma unroll
            for (int j = 0; j < 4; j++) Bs[bk][bn + j] = toF(bp2[j]);
        }
        __syncthreads();
#pragma unroll
        for (int kk = 0; kk < BK; kk++) {
            float ra[4], rb[4];
#pragma unroll
            for (int i = 0; i < 4; i++) ra[i] = As[kk][ty * 4 + i];
#pragma unroll
            for (int j = 0; j < 4; j++) rb[j] = Bs[kk][tx * 4 + j];
#pragma unroll
            for (int i = 0; i < 4; i++)
#pragma unroll
                for (int j = 0; j < 4; j++) acc[i][j] += ra[i] * rb[j];
        }
        __syncthreads();
    }
#pragma unroll
    for (int i = 0; i < 4; i++) {
        const int r = rowBase + ty * 4 + i;
#pragma unroll
        for (int j = 0; j < 4; j++) {
            const int c = colBase + tx * 4 + j;
            float v = acc[i][j] + toF(bias[c]);
            v = v > 0.f ? v : 0.f;
            stT(&Out[(size_t)r * N + c], v);
        }
    }
}

// ---------------- fast tanh (bf16 mode only; f32 mode keeps exact tanhf) ----
__device__ __forceinline__ float tanh_fast(float x) {
    float ax = fminf(fabsf(x), 12.0f);
    float e  = __expf(2.0f * ax);
    float t  = 1.0f - __fdividef(2.0f, e + 1.0f);
    return copysignf(t, x);
}

// ---------------- Fused scores -> masked softmax -> agg. One WG per (b, p).
template<typename T, int MODE>
__global__ __launch_bounds__(256) void attn_fused(
    const int* __restrict__ flag,
    const float* __restrict__ pa,          // [B*LP, H] f32 (ws)
    const float* __restrict__ an,          // [B*LA, H] f32 (ws)
    const T* __restrict__ answer,          // [B*LA, DA]
    const int* __restrict__ amask,         // [B, LA]
    const T* __restrict__ ww,              // [H]
    const T* __restrict__ wbp,             // [1]
    T* __restrict__ agg_out)               // [B*LP, DA] (d_out tail)
{
    if (*flag != MODE) return;
    __shared__ float s_pa[HH_];
    __shared__ float s_ww[HH_];
    __shared__ float s_sc[LA_];
    __shared__ float s_at[LA_];

    const int bp_idx = blockIdx.x;      // b*LP + p
    const int b = bp_idx >> 9;          // / LP_
    const int tid = threadIdx.x;

    for (int h = tid; h < HH_; h += 256) {
        s_pa[h] = pa[(size_t)bp_idx * HH_ + h];
        s_ww[h] = toF(ww[h]);
    }
    __syncthreads();

    // scores: 32 a-values, 8 lanes each
    const int a = tid >> 3, l = tid & 7;
    const float* anr = an + (size_t)(b * LA_ + a) * HH_;
    float part = 0.f;
#pragma unroll 4
    for (int h = l; h < HH_; h += 8) {
        float v = s_pa[h] + anr[h];
        float th = (MODE == 0) ? tanh_fast(v) : tanhf(v);
        part += th * s_ww[h];
    }
    part += __shfl_down(part, 4, 8);
    part += __shfl_down(part, 2, 8);
    part += __shfl_down(part, 1, 8);
    if (l == 0) {
        float sc = part + toF(wbp[0]);
        if (amask[b * LA_ + a] == 0) sc = -1e8f;
        s_sc[a] = sc;
    }
    __syncthreads();

    // softmax over LA_=32
    if (tid < 32) {
        float s = s_sc[tid];
        float m = s;
        for (int off = 16; off > 0; off >>= 1) m = fmaxf(m, __shfl_xor(m, off, 32));
        float e = __expf(s - m);
        float sum = e;
        for (int off = 16; off > 0; off >>= 1) sum += __shfl_xor(sum, off, 32);
        s_at[tid] = e / sum;
    }
    __syncthreads();

    // agg[d] = sum_a attn[a] * answer[b,a,d]
    const T* ansb = answer + (size_t)b * LA_ * DA_;
    for (int d = tid; d < DA_; d += 256) {
        float acc = 0.f;
#pragma unroll
        for (int a2 = 0; a2 < LA_; a2++)
            acc += s_at[a2] * toF(ansb[a2 * DA_ + d]);
        stT(&agg_out[(size_t)bp_idx * DA_ + d], acc);
    }
}

extern "C" void kernel_launch(void* const* d_in, const int* in_sizes, int n_in,
                              void* d_out, int out_size, void* d_ws, size_t ws_size,
                              hipStream_t stream) {
    const int* amask = (const int*)d_in[3];

    // Workspace layout:
    //   [0..15]  flag
    //   pa f32 [8192,512]   16 MB
    //   an f32 [512,512]     1 MB
    //   WpT bf16 [512,1024]  1 MB   (bf16 mode only)
    //   WaT bf16 [512,512]  .5 MB
    //   WoT bf16 [1024,1536] 3 MB
    int*      flag  = (int*)d_ws;
    float*    pa_ws = (float*)((char*)d_ws + 16);
    float*    an_ws = pa_ws + (size_t)B_ * LP_ * HH_;
    ushort_t* WpT   = (ushort_t*)(an_ws + (size_t)B_ * LA_ * HH_);
    ushort_t* WaT   = WpT + (size_t)HH_ * DP_;
    ushort_t* WoT   = WaT + (size_t)HH_ * DA_;
    const size_t WS_NEED = 16
        + (size_t)B_ * LP_ * HH_ * 4 + (size_t)B_ * LA_ * HH_ * 4
        + ((size_t)HH_ * DP_ + (size_t)HH_ * DA_ + (size_t)DO_ * (DP_ + DA_)) * 2;
    const bool mfma_ok = (ws_size >= WS_NEED);

    const int M1 = B_ * LA_;   // 512
    const int M2 = B_ * LP_;   // 8192

    detect_mode<<<1, 1024, 0, stream>>>((const unsigned short*)d_in[0], flag);

    // ---- bf16-mode path (MODE 0) ----
    {
        const ushort_t* ppl    = (const ushort_t*)d_in[0];
        const ushort_t* answer = (const ushort_t*)d_in[2];
        const ushort_t* Wp     = (const ushort_t*)d_in[4];
        const ushort_t* bp     = (const ushort_t*)d_in[5];
        const ushort_t* Wa     = (const ushort_t*)d_in[6];
        const ushort_t* ba     = (const ushort_t*)d_in[7];
        const __hip_bfloat16* ww = (const __hip_bfloat16*)d_in[8];
        const __hip_bfloat16* wb = (const __hip_bfloat16*)d_in[9];
        const ushort_t* Wo     = (const ushort_t*)d_in[10];
        const ushort_t* bo     = (const ushort_t*)d_in[11];
        __hip_bfloat16* aligned_out = (__hip_bfloat16*)d_out;
        __hip_bfloat16* agg_out     = aligned_out + (size_t)B_ * LP_ * DP_;

        if (mfma_ok) {
            // weight transposes (flag-gated no-ops in f32 mode)
            transpose_bf16<<<(DA_ / 32) * (HH_ / 32), 256, 0, stream>>>(
                flag, Wa, WaT, DA_, HH_);
            transpose_bf16<<<(DP_ / 32) * (HH_ / 32), 256, 0, stream>>>(
                flag, Wp, WpT, DP_, HH_);
            transpose_bf16<<<((DP_ + DA_) / 32) * (DO_ / 32), 256, 0, stream>>>(
                flag, Wo, WoT, DP_ + DA_, DO_);

            // an = answer @ Wa + ba   (M=512, N=512, K=512)
            gemm_mfma<64, 64, 0, 0, 1><<<(M1 / 64) * (HH_ / 64), 256, 0, stream>>>(
                flag, answer, nullptr, WaT, ba, an_ws, HH_, DA_);
            // pa = ppl @ Wp + bp      (M=8192, N=512, K=1024)
            gemm_mfma<128, 128, 0, 0, 1><<<(M2 / 128) * (HH_ / 128), 256, 0, stream>>>(
                flag, ppl, nullptr, WpT, bp, pa_ws, HH_, DP_);
            attn_fused<__hip_bfloat16, 0><<<M2, 256, 0, stream>>>(
                flag, pa_ws, an_ws, (const __hip_bfloat16*)answer, amask, ww, wb, agg_out);
            // aligned = relu(concat(ppl, agg) @ Wo + bo)  (M=8192, N=1024, K=1536)
            gemm_mfma<128, 128, 1, 1, 0><<<(M2 / 128) * (DO_ / 128), 256, 0, stream>>>(
                flag, ppl, (const ushort_t*)agg_out, WoT, bo, aligned_out,
                DO_, DP_ + DA_);
        } else {
            // legacy scalar fallback
            gemm_bias<__hip_bfloat16, 0><<<(M1 / BM) * (HH_ / BN), 256, 0, stream>>>(
                flag, (const __hip_bfloat16*)answer, (const __hip_bfloat16*)Wa,
                (const __hip_bfloat16*)ba, an_ws, M1, HH_, DA_);
            gemm_bias<__hip_bfloat16, 0><<<(M2 / BM) * (HH_ / BN), 256, 0, stream>>>(
                flag, (const __hip_bfloat16*)ppl, (const __hip_bfloat16*)Wp,
                (const __hip_bfloat16*)bp, pa_ws, M2, HH_, DP_);
            attn_fused<__hip_bfloat16, 0><<<M2, 256, 0, stream>>>(
                flag, pa_ws, an_ws, (const __hip_bfloat16*)answer, amask, ww, wb, agg_out);
            gemm_concat_relu<__hip_bfloat16, 0><<<(M2 / BM) * (DO_ / BN), 256, 0, stream>>>(
                flag, (const __hip_bfloat16*)ppl, agg_out, (const __hip_bfloat16*)Wo,
                (const __hip_bfloat16*)bo, aligned_out, M2);
        }
    }

    // ---- f32-mode path (MODE 1, unchanged scalar) ----
    {
        const float* ppl    = (const float*)d_in[0];
        const float* answer = (const float*)d_in[2];
        const float* Wp     = (const float*)d_in[4];
        const float* bp     = (const float*)d_in[5];
        const float* Wa     = (const float*)d_in[6];
        const float* ba     = (const float*)d_in[7];
        const float* ww     = (const float*)d_in[8];
        const float* wb     = (const float*)d_in[9];
        const float* Wo     = (const float*)d_in[10];
        const float* bo     = (const float*)d_in[11];
        float* aligned_out = (float*)d_out;
        float* agg_out     = aligned_out + (size_t)B_ * LP_ * DP_;

        gemm_bias<float, 1><<<(M1 / BM) * (HH_ / BN), 256, 0, stream>>>(
            flag, answer, Wa, ba, an_ws, M1, HH_, DA_);
        gemm_bias<float, 1><<<(M2 / BM) * (HH_ / BN), 256, 0, stream>>>(
            flag, ppl, Wp, bp, pa_ws, M2, HH_, DP_);
        attn_fused<float, 1><<<M2, 256, 0, stream>>>(
            flag, pa_ws, an_ws, answer, amask, ww, wb, agg_out);
        gemm_concat_relu<float, 1><<<(M2 / BM) * (DO_ / BN), 256, 0, stream>>>(
            flag, ppl, agg_out, Wo, bo, aligned_out, M2);
    }
}

// Round 2
// 945.802 us; speedup vs baseline: 1.0092x; 1.0048x over previous
//
#include <hip/hip_runtime.h>
#include <hip/hip_bf16.h>
#include <math.h>

// Problem constants
#define B_  16
#define LP_ 512
#define LA_ 32
#define DP_ 1024
#define DA_ 512
#define HH_ 512
#define DO_ 1024

typedef unsigned short ushort_t;
typedef __attribute__((ext_vector_type(8))) short bf16x8;
typedef __attribute__((ext_vector_type(4))) float f32x4;

// Dtype helpers: MODE 0 = bf16 storage, MODE 1 = f32 storage.
__device__ __forceinline__ float toF(float x){ return x; }
__device__ __forceinline__ float toF(__hip_bfloat16 x){ return __bfloat162float(x); }
__device__ __forceinline__ void stT(float* p, float v){ *p = v; }
__device__ __forceinline__ void stT(__hip_bfloat16* p, float v){ *p = __float2bfloat16(v); }

// ---------------- dtype detector ----------------
// f32 storage -> low mantissa halves look like random bf16 with huge exponents.
__global__ void detect_mode(const unsigned short* __restrict__ raw,
                            int* __restrict__ flag) {
    __shared__ int cnt;
    if (threadIdx.x == 0) cnt = 0;
    __syncthreads();
    int e = (raw[threadIdx.x] >> 7) & 0xFF;
    if (e >= 160) atomicAdd(&cnt, 1);
    __syncthreads();
    if (threadIdx.x == 0) *flag = (cnt > 0) ? 1 : 0;
}

// ---------------- bf16 transpose: src[R][C] -> dst[C][R] (MODE 0 only) ----
__global__ __launch_bounds__(256) void transpose_bf16(
    const int* __restrict__ flag,
    const ushort_t* __restrict__ src, ushort_t* __restrict__ dst,
    int R, int C)
{
    if (*flag != 0) return;
    __shared__ ushort_t tile[32][33];
    const int nbx = C / 32;
    const int bx = blockIdx.x % nbx;   // C tile
    const int by = blockIdx.x / nbx;   // R tile
    const int tx = threadIdx.x % 32, ty = threadIdx.x / 32;  // 32x8
    const int c0 = bx * 32, r0 = by * 32;
#pragma unroll
    for (int i = ty; i < 32; i += 8)
        tile[i][tx] = src[(size_t)(r0 + i) * C + c0 + tx];
    __syncthreads();
#pragma unroll
    for (int i = ty; i < 32; i += 8)
        dst[(size_t)(c0 + i) * R + r0 + tx] = tile[tx][i];
}

// ---------------- MFMA bf16 GEMM ----------------
// C[M,N] = A[M,K] @ B[K,N] + bias, with B supplied TRANSPOSED as BT[N,K].
// 256 threads = 4 waves in 2x2; 16x16x32 bf16 MFMA.
// Correctness note: A and B fragments are loaded with the SAME (lane-group,
// slot)->k convention (8 contiguous k at (lane>>4)*8). Since the MFMA pairs
// A-slot s of group g with B-slot s of group g, ANY internal HW k-permutation
// cancels -> exact dot product regardless of the undocumented input layout.
// C/D layout (HW-verified m89): col = lane&15, row = (lane>>4)*4 + reg.
// CONCAT: A = [A0 (DP_ cols) | A1 (DA_ cols)]. OUTF32: f32 out else bf16.
template<int BMt, int BNt, int CONCAT, int RELU, int OUTF32>
__global__ __launch_bounds__(256) void gemm_mfma(
    const int* __restrict__ flag,
    const ushort_t* __restrict__ A0,
    const ushort_t* __restrict__ A1,
    const ushort_t* __restrict__ BT,
    const ushort_t* __restrict__ bias,
    void* __restrict__ Cout,
    int N, int K)
{
    if (*flag != 0) return;
    constexpr int SA = 40;   // 40 ushort = 80 B row stride: 16B-aligned, banks spread
    __shared__ ushort_t As[BMt * SA];
    __shared__ ushort_t Bs[BNt * SA];
    const int tid = threadIdx.x;
    const int nbx = N / BNt;
    const int colBase = (blockIdx.x % nbx) * BNt;
    const int rowBase = (blockIdx.x / nbx) * BMt;
    const int wid = tid >> 6, lane = tid & 63;
    const int wr = wid >> 1, wc = wid & 1;
    const int lrow = lane & 15;
    const int lk8 = (lane >> 4) * 8;    // contiguous 8-k slot base
    constexpr int FM = BMt / 32, FN = BNt / 32;

    f32x4 acc[FM][FN] = {};

    for (int k0 = 0; k0 < K; k0 += 32) {
        // stage A tile [BMt][32]
#pragma unroll
        for (int c = 0; c < BMt / 64; c++) {
            const int chunk = tid + c * 256;           // BMt*4 chunks of 8 bf16
            const int row = chunk >> 2, k8 = (chunk & 3) * 8;
            const int gk = k0 + k8;
            const ushort_t* ap;
            if (CONCAT) {
                ap = (gk < DP_) ? A0 + (size_t)(rowBase + row) * DP_ + gk
                                : A1 + (size_t)(rowBase + row) * DA_ + (gk - DP_);
            } else {
                ap = A0 + (size_t)(rowBase + row) * K + gk;
            }
            *(uint4*)&As[row * SA + k8] = *(const uint4*)ap;
        }
        // stage BT tile [BNt][32]
#pragma unroll
        for (int c = 0; c < BNt / 64; c++) {
            const int chunk = tid + c * 256;
            const int row = chunk >> 2, k8 = (chunk & 3) * 8;
            *(uint4*)&Bs[row * SA + k8] =
                *(const uint4*)(BT + (size_t)(colBase + row) * K + k0 + k8);
        }
        __syncthreads();

        bf16x8 af[FM], bfr[FN];
#pragma unroll
        for (int m = 0; m < FM; m++)
            af[m] = *(const bf16x8*)&As[(wr * (BMt / 2) + m * 16 + lrow) * SA + lk8];
#pragma unroll
        for (int n = 0; n < FN; n++)
            bfr[n] = *(const bf16x8*)&Bs[(wc * (BNt / 2) + n * 16 + lrow) * SA + lk8];
#pragma unroll
        for (int m = 0; m < FM; m++)
#pragma unroll
            for (int n = 0; n < FN; n++)
                acc[m][n] = __builtin_amdgcn_mfma_f32_16x16x32_bf16(
                    af[m], bfr[n], acc[m][n], 0, 0, 0);
        __syncthreads();
    }

    // epilogue: C/D layout col=lane&15, row=(lane>>4)*4+reg
#pragma unroll
    for (int n = 0; n < FN; n++) {
        const int gc = colBase + wc * (BNt / 2) + n * 16 + lrow;
        const float bv = __bfloat162float(*(const __hip_bfloat16*)&bias[gc]);
#pragma unroll
        for (int m = 0; m < FM; m++) {
            const int gr0 = rowBase + wr * (BMt / 2) + m * 16 + (lane >> 4) * 4;
#pragma unroll
            for (int r = 0; r < 4; r++) {
                float v = acc[m][n][r] + bv;
                if (RELU) v = v > 0.f ? v : 0.f;
                if (OUTF32)
                    ((float*)Cout)[(size_t)(gr0 + r) * N + gc] = v;
                else
                    ((__hip_bfloat16*)Cout)[(size_t)(gr0 + r) * N + gc] = __float2bfloat16(v);
            }
        }
    }
}

// ---------------- Legacy scalar GEMMs (f32 mode + ws-fallback) ----------------
#define BM 64
#define BN 64
#define BK 16

template<typename T, int MODE>
__global__ __launch_bounds__(256) void gemm_bias(
    const int* __restrict__ flag,
    const T* __restrict__ A,
    const T* __restrict__ Bm,
    const T* __restrict__ bias,
    float* __restrict__ C, int M, int N, int K)
{
    if (*flag != MODE) return;
    __shared__ float As[BK][BM + 1];
    __shared__ float Bs[BK][BN + 1];
    const int tid = threadIdx.x;
    const int nbx = N / BN;
    const int bx = blockIdx.x % nbx;
    const int by = blockIdx.x / nbx;
    const int rowBase = by * BM, colBase = bx * BN;
    const int ty = tid / 16, tx = tid % 16;
    float acc[4][4] = {};

    for (int k0 = 0; k0 < K; k0 += BK) {
        {
            const int am = tid >> 2, ak = (tid & 3) * 4;
            const T* ap = A + (size_t)(rowBase + am) * K + k0 + ak;
#pragma unroll
            for (int j = 0; j < 4; j++) As[ak + j][am] = toF(ap[j]);
        }
        {
            const int bk = tid >> 4, bn = (tid & 15) * 4;
            const T* bp2 = Bm + (size_t)(k0 + bk) * N + colBase + bn;
#pragma unroll
            for (int j = 0; j < 4; j++) Bs[bk][bn + j] = toF(bp2[j]);
        }
        __syncthreads();
#pragma unroll
        for (int kk = 0; kk < BK; kk++) {
            float ra[4], rb[4];
#pragma unroll
            for (int i = 0; i < 4; i++) ra[i] = As[kk][ty * 4 + i];
#pragma unroll
            for (int j = 0; j < 4; j++) rb[j] = Bs[kk][tx * 4 + j];
#pragma unroll
            for (int i = 0; i < 4; i++)
#pragma unroll
                for (int j = 0; j < 4; j++) acc[i][j] += ra[i] * rb[j];
        }
        __syncthreads();
    }
#pragma unroll
    for (int i = 0; i < 4; i++) {
        const int r = rowBase + ty * 4 + i;
#pragma unroll
        for (int j = 0; j < 4; j++) {
            const int c = colBase + tx * 4 + j;
            C[(size_t)r * N + c] = acc[i][j] + toF(bias[c]);
        }
    }
}

template<typename T, int MODE>
__global__ __launch_bounds__(256) void gemm_concat_relu(
    const int* __restrict__ flag,
    const T* __restrict__ A0,     // ppl [M, DP_]
    const T* __restrict__ A1,     // agg [M, DA_]
    const T* __restrict__ Bm,     // Wo [DP_+DA_, DO_]
    const T* __restrict__ bias,   // bo [DO_]
    T* __restrict__ Out, int M)
{
    if (*flag != MODE) return;
    const int N = DO_, K = DP_ + DA_;
    __shared__ float As[BK][BM + 1];
    __shared__ float Bs[BK][BN + 1];
    const int tid = threadIdx.x;
    const int nbx = N / BN;
    const int bx = blockIdx.x % nbx;
    const int by = blockIdx.x / nbx;
    const int rowBase = by * BM, colBase = bx * BN;
    const int ty = tid / 16, tx = tid % 16;
    float acc[4][4] = {};

    for (int k0 = 0; k0 < K; k0 += BK) {
        {
            const int am = tid >> 2, ak = (tid & 3) * 4;
            const int gk = k0 + ak;
            const T* ap = (gk < DP_)
                ? A0 + (size_t)(rowBase + am) * DP_ + gk
                : A1 + (size_t)(rowBase + am) * DA_ + (gk - DP_);
#pragma unroll
            for (int j = 0; j < 4; j++) As[ak + j][am] = toF(ap[j]);
        }
        {
            const int bk = tid >> 4, bn = (tid & 15) * 4;
            const T* bp2 = Bm + (size_t)(k0 + bk) * N + colBase + bn;
#pragma unroll
            for (int j = 0; j < 4; j++) Bs[bk][bn + j] = toF(bp2[j]);
        }
        __syncthreads();
#pragma unroll
        for (int kk = 0; kk < BK; kk++) {
            float ra[4], rb[4];
#pragma unroll
            for (int i = 0; i < 4; i++) ra[i] = As[kk][ty * 4 + i];
#pragma unroll
            for (int j = 0; j < 4; j++) rb[j] = Bs[kk][tx * 4 + j];
#pragma unroll
            for (int i = 0; i < 4; i++)
#pragma unroll
                for (int j = 0; j < 4; j++) acc[i][j] += ra[i] * rb[j];
        }
        __syncthreads();
    }
#pragma unroll
    for (int i = 0; i < 4; i++) {
        const int r = rowBase + ty * 4 + i;
#pragma unroll
        for (int j = 0; j < 4; j++) {
            const int c = colBase + tx * 4 + j;
            float v = acc[i][j] + toF(bias[c]);
            v = v > 0.f ? v : 0.f;
            stT(&Out[(size_t)r * N + c], v);
        }
    }
}

// ---------------- fast tanh (bf16 mode only; f32 mode keeps exact tanhf) ----
__device__ __forceinline__ float tanh_fast(float x) {
    float ax = fminf(fabsf(x), 12.0f);
    float e  = __expf(2.0f * ax);
    float t  = 1.0f - __fdividef(2.0f, e + 1.0f);
    return copysignf(t, x);
}

// ---------------- Fused scores -> masked softmax -> agg. One WG per (b, p).
// T = answer/ww/out dtype; PAT = pa storage dtype (workspace tiering).
template<typename T, typename PAT, int MODE>
__global__ __launch_bounds__(256) void attn_fused(
    const int* __restrict__ flag,
    const PAT* __restrict__ pa,            // [B*LP, H] (ws)
    const float* __restrict__ an,          // [B*LA, H] f32 (ws)
    const T* __restrict__ answer,          // [B*LA, DA]
    const int* __restrict__ amask,         // [B, LA]
    const T* __restrict__ ww,              // [H]
    const T* __restrict__ wbp,             // [1]
    T* __restrict__ agg_out)               // [B*LP, DA] (d_out tail)
{
    if (*flag != MODE) return;
    __shared__ float s_pa[HH_];
    __shared__ float s_ww[HH_];
    __shared__ float s_sc[LA_];
    __shared__ float s_at[LA_];

    const int bp_idx = blockIdx.x;      // b*LP + p
    const int b = bp_idx >> 9;          // / LP_
    const int tid = threadIdx.x;

    for (int h = tid; h < HH_; h += 256) {
        s_pa[h] = toF(pa[(size_t)bp_idx * HH_ + h]);
        s_ww[h] = toF(ww[h]);
    }
    __syncthreads();

    // scores: 32 a-values, 8 lanes each
    const int a = tid >> 3, l = tid & 7;
    const float* anr = an + (size_t)(b * LA_ + a) * HH_;
    float part = 0.f;
#pragma unroll 4
    for (int h = l; h < HH_; h += 8) {
        float v = s_pa[h] + anr[h];
        float th = (MODE == 0) ? tanh_fast(v) : tanhf(v);
        part += th * s_ww[h];
    }
    part += __shfl_down(part, 4, 8);
    part += __shfl_down(part, 2, 8);
    part += __shfl_down(part, 1, 8);
    if (l == 0) {
        float sc = part + toF(wbp[0]);
        if (amask[b * LA_ + a] == 0) sc = -1e8f;
        s_sc[a] = sc;
    }
    __syncthreads();

    // softmax over LA_=32
    if (tid < 32) {
        float s = s_sc[tid];
        float m = s;
        for (int off = 16; off > 0; off >>= 1) m = fmaxf(m, __shfl_xor(m, off, 32));
        float e = __expf(s - m);
        float sum = e;
        for (int off = 16; off > 0; off >>= 1) sum += __shfl_xor(sum, off, 32);
        s_at[tid] = e / sum;
    }
    __syncthreads();

    // agg[d] = sum_a attn[a] * answer[b,a,d]
    const T* ansb = answer + (size_t)b * LA_ * DA_;
    for (int d = tid; d < DA_; d += 256) {
        float acc = 0.f;
#pragma unroll
        for (int a2 = 0; a2 < LA_; a2++)
            acc += s_at[a2] * toF(ansb[a2 * DA_ + d]);
        stT(&agg_out[(size_t)bp_idx * DA_ + d], acc);
    }
}

extern "C" void kernel_launch(void* const* d_in, const int* in_sizes, int n_in,
                              void* d_out, int out_size, void* d_ws, size_t ws_size,
                              hipStream_t stream) {
    const int* amask = (const int*)d_in[3];

    const int M1 = B_ * LA_;   // 512
    const int M2 = B_ * LP_;   // 8192

    // ---- workspace budgets (bytes) ----
    const size_t SZ_PA_F32 = (size_t)M2 * HH_ * 4;          // 16 MB
    const size_t SZ_PA_B16 = (size_t)M2 * HH_ * 2;          //  8 MB
    const size_t SZ_AN_F32 = (size_t)M1 * HH_ * 4;          //  1 MB
    const size_t SZ_WT     = ((size_t)HH_ * DP_ + (size_t)HH_ * DA_
                              + (size_t)DO_ * (DP_ + DA_)) * 2;  // 4.5 MB
    const size_t NEED_A = 16 + SZ_PA_F32 + SZ_AN_F32 + SZ_WT;    // 22,544,400
    const size_t NEED_B = 16 + SZ_PA_B16 + SZ_AN_F32 + SZ_WT;    // 14,155,792

    int* flag = (int*)d_ws;

    // f32-mode layout (also scalar-fallback layout): pa f32 + an f32
    float* paF = (float*)((char*)d_ws + 16);
    float* anF = paF + (size_t)M2 * HH_;

    detect_mode<<<1, 1024, 0, stream>>>((const unsigned short*)d_in[0], flag);

    // ---- bf16-mode path (MODE 0) ----
    {
        const ushort_t* ppl    = (const ushort_t*)d_in[0];
        const ushort_t* answer = (const ushort_t*)d_in[2];
        const ushort_t* Wp     = (const ushort_t*)d_in[4];
        const ushort_t* bp     = (const ushort_t*)d_in[5];
        const ushort_t* Wa     = (const ushort_t*)d_in[6];
        const ushort_t* ba     = (const ushort_t*)d_in[7];
        const __hip_bfloat16* ww = (const __hip_bfloat16*)d_in[8];
        const __hip_bfloat16* wb = (const __hip_bfloat16*)d_in[9];
        const ushort_t* Wo     = (const ushort_t*)d_in[10];
        const ushort_t* bo     = (const ushort_t*)d_in[11];
        __hip_bfloat16* aligned_out = (__hip_bfloat16*)d_out;
        __hip_bfloat16* agg_out     = aligned_out + (size_t)B_ * LP_ * DP_;

        const bool tierA = (ws_size >= NEED_A);
        const bool tierB = (ws_size >= NEED_B);

        if (tierA || tierB) {
            // layout: [pa (f32|b16)] [an f32] [WpT] [WaT] [WoT]
            char* cur = (char*)d_ws + 16;
            void* pa_any = cur;            cur += tierA ? SZ_PA_F32 : SZ_PA_B16;
            float* an_ws = (float*)cur;    cur += SZ_AN_F32;
            ushort_t* WpT = (ushort_t*)cur; cur += (size_t)HH_ * DP_ * 2;
            ushort_t* WaT = (ushort_t*)cur; cur += (size_t)HH_ * DA_ * 2;
            ushort_t* WoT = (ushort_t*)cur;

            transpose_bf16<<<(DA_ / 32) * (HH_ / 32), 256, 0, stream>>>(
                flag, Wa, WaT, DA_, HH_);
            transpose_bf16<<<(DP_ / 32) * (HH_ / 32), 256, 0, stream>>>(
                flag, Wp, WpT, DP_, HH_);
            transpose_bf16<<<((DP_ + DA_) / 32) * (DO_ / 32), 256, 0, stream>>>(
                flag, Wo, WoT, DP_ + DA_, DO_);

            // an = answer @ Wa + ba   (M=512, N=512, K=512) -> f32
            gemm_mfma<64, 64, 0, 0, 1><<<(M1 / 64) * (HH_ / 64), 256, 0, stream>>>(
                flag, answer, nullptr, WaT, ba, an_ws, HH_, DA_);

            if (tierA) {
                // pa f32
                gemm_mfma<128, 128, 0, 0, 1><<<(M2 / 128) * (HH_ / 128), 256, 0, stream>>>(
                    flag, ppl, nullptr, WpT, bp, pa_any, HH_, DP_);
                attn_fused<__hip_bfloat16, float, 0><<<M2, 256, 0, stream>>>(
                    flag, (const float*)pa_any, an_ws, (const __hip_bfloat16*)answer,
                    amask, ww, wb, agg_out);
            } else {
                // pa bf16 (compact)
                gemm_mfma<128, 128, 0, 0, 0><<<(M2 / 128) * (HH_ / 128), 256, 0, stream>>>(
                    flag, ppl, nullptr, WpT, bp, pa_any, HH_, DP_);
                attn_fused<__hip_bfloat16, __hip_bfloat16, 0><<<M2, 256, 0, stream>>>(
                    flag, (const __hip_bfloat16*)pa_any, an_ws,
                    (const __hip_bfloat16*)answer, amask, ww, wb, agg_out);
            }

            // aligned = relu(concat(ppl, agg) @ Wo + bo)  (M=8192, N=1024, K=1536)
            gemm_mfma<128, 128, 1, 1, 0><<<(M2 / 128) * (DO_ / 128), 256, 0, stream>>>(
                flag, ppl, (const ushort_t*)agg_out, WoT, bo, aligned_out,
                DO_, DP_ + DA_);
        } else {
            // legacy scalar fallback (uses paF/anF f32 layout)
            gemm_bias<__hip_bfloat16, 0><<<(M1 / BM) * (HH_ / BN), 256, 0, stream>>>(
                flag, (const __hip_bfloat16*)answer, (const __hip_bfloat16*)Wa,
                (const __hip_bfloat16*)ba, anF, M1, HH_, DA_);
            gemm_bias<__hip_bfloat16, 0><<<(M2 / BM) * (HH_ / BN), 256, 0, stream>>>(
                flag, (const __hip_bfloat16*)ppl, (const __hip_bfloat16*)Wp,
                (const __hip_bfloat16*)bp, paF, M2, HH_, DP_);
            attn_fused<__hip_bfloat16, float, 0><<<M2, 256, 0, stream>>>(
                flag, paF, anF, (const __hip_bfloat16*)answer, amask, ww, wb, agg_out);
            gemm_concat_relu<__hip_bfloat16, 0><<<(M2 / BM) * (DO_ / BN), 256, 0, stream>>>(
                flag, (const __hip_bfloat16*)ppl, agg_out, (const __hip_bfloat16*)Wo,
                (const __hip_bfloat16*)bo, aligned_out, M2);
        }
    }

    // ---- f32-mode path (MODE 1, scalar insurance; believed dead) ----
    {
        const float* ppl    = (const float*)d_in[0];
        const float* answer = (const float*)d_in[2];
        const float* Wp     = (const float*)d_in[4];
        const float* bp     = (const float*)d_in[5];
        const float* Wa     = (const float*)d_in[6];
        const float* ba     = (const float*)d_in[7];
        const float* ww     = (const float*)d_in[8];
        const float* wb     = (const float*)d_in[9];
        const float* Wo     = (const float*)d_in[10];
        const float* bo     = (const float*)d_in[11];
        float* aligned_out = (float*)d_out;
        float* agg_out     = aligned_out + (size_t)B_ * LP_ * DP_;

        gemm_bias<float, 1><<<(M1 / BM) * (HH_ / BN), 256, 0, stream>>>(
            flag, answer, Wa, ba, anF, M1, HH_, DA_);
        gemm_bias<float, 1><<<(M2 / BM) * (HH_ / BN), 256, 0, stream>>>(
            flag, ppl, Wp, bp, paF, M2, HH_, DP_);
        attn_fused<float, float, 1><<<M2, 256, 0, stream>>>(
            flag, paF, anF, answer, amask, ww, wb, agg_out);
        gemm_concat_relu<float, 1><<<(M2 / BM) * (DO_ / BN), 256, 0, stream>>>(
            flag, ppl, agg_out, Wo, bo, aligned_out, M2);
    }
}

// Round 3
// 371.394 us; speedup vs baseline: 2.5701x; 2.5466x over previous
//
#include <hip/hip_runtime.h>
#include <hip/hip_bf16.h>
#include <math.h>

// Problem constants
#define B_  16
#define LP_ 512
#define LA_ 32
#define DP_ 1024
#define DA_ 512
#define HH_ 512
#define DO_ 1024

typedef unsigned short ushort_t;
typedef __attribute__((ext_vector_type(8))) short bf16x8;
typedef __attribute__((ext_vector_type(4))) float f32x4;

// Dtype helpers: MODE 0 = bf16 storage, MODE 1 = f32 storage.
__device__ __forceinline__ float toF(float x){ return x; }
__device__ __forceinline__ float toF(__hip_bfloat16 x){ return __bfloat162float(x); }
__device__ __forceinline__ void stT(float* p, float v){ *p = v; }
__device__ __forceinline__ void stT(__hip_bfloat16* p, float v){ *p = __float2bfloat16(v); }

__device__ __forceinline__ ushort_t f2bs(float x) {
    __hip_bfloat16 b = __float2bfloat16(x);
    return *(ushort_t*)&b;
}
__device__ __forceinline__ float bs2f(ushort_t u) {
    __hip_bfloat16 b = *(__hip_bfloat16*)&u;
    return __bfloat162float(b);
}

// ---------------- dtype detector ----------------
// f32 storage -> low mantissa halves look like random bf16 with huge exponents.
__global__ void detect_mode(const unsigned short* __restrict__ raw,
                            int* __restrict__ flag) {
    __shared__ int cnt;
    if (threadIdx.x == 0) cnt = 0;
    __syncthreads();
    int e = (raw[threadIdx.x] >> 7) & 0xFF;
    if (e >= 160) atomicAdd(&cnt, 1);
    __syncthreads();
    if (threadIdx.x == 0) *flag = (cnt > 0) ? 1 : 0;
}

// ================= MODE 1 (f32 storage) — split-bf16 MFMA path =============

// Transpose f32 src[R][C] -> bf16 hi/lo planes dst[C][R]. MODE 1 only.
__global__ __launch_bounds__(256) void transpose_split_f32(
    const int* __restrict__ flag,
    const float* __restrict__ src,
    ushort_t* __restrict__ dstH, ushort_t* __restrict__ dstL,
    int R, int C)
{
    if (*flag != 1) return;
    __shared__ float tile[32][33];
    const int nbx = C / 32;
    const int bx = blockIdx.x % nbx;   // C tile
    const int by = blockIdx.x / nbx;   // R tile
    const int tx = threadIdx.x % 32, ty = threadIdx.x / 32;  // 32x8
    const int c0 = bx * 32, r0 = by * 32;
#pragma unroll
    for (int i = ty; i < 32; i += 8)
        tile[i][tx] = src[(size_t)(r0 + i) * C + c0 + tx];
    __syncthreads();
#pragma unroll
    for (int i = ty; i < 32; i += 8) {
        float x = tile[tx][i];
        ushort_t h = f2bs(x);
        float lo = x - bs2f(h);
        dstH[(size_t)(c0 + i) * R + r0 + tx] = h;
        dstL[(size_t)(c0 + i) * R + r0 + tx] = f2bs(lo);
    }
}

// Split-bf16 MFMA GEMM: C_f32[M,N] = A_f32[M,K] @ B[K,N] + bias_f32, where B is
// given as transposed bf16 hi/lo planes BTH/BTL [N][K]. Per K-step, each
// fragment pair does 3 MFMA: Ah*Bh + Ah*Bl + Al*Bh (Al*Bl dropped, ~1e-5).
// A/B fragments use the SAME (lane-group, slot)->k convention (8 contiguous k
// at (lane>>4)*8) so any HW k-permutation cancels. C/D: col=lane&15,
// row=(lane>>4)*4+reg [HW-verified m89].
// CONCAT: A = [A0 (DP_ cols) | A1 (DA_ cols)].
template<int BMt, int BNt, int CONCAT, int RELU>
__global__ __launch_bounds__(256) void gemm_mfma_split(
    const int* __restrict__ flag,
    const float* __restrict__ A0,
    const float* __restrict__ A1,
    const ushort_t* __restrict__ BTH,
    const ushort_t* __restrict__ BTL,
    const float* __restrict__ bias,
    float* __restrict__ Cout,
    int N, int K)
{
    if (*flag != 1) return;
    constexpr int SA = 40;   // 80 B row stride: 16B-aligned b128 reads, banks spread
    __shared__ ushort_t AsH[BMt * SA];
    __shared__ ushort_t AsL[BMt * SA];
    __shared__ ushort_t BsH[BNt * SA];
    __shared__ ushort_t BsL[BNt * SA];
    const int tid = threadIdx.x;
    const int nbx = N / BNt;
    const int colBase = (blockIdx.x % nbx) * BNt;
    const int rowBase = (blockIdx.x / nbx) * BMt;
    const int wid = tid >> 6, lane = tid & 63;
    const int wr = wid >> 1, wc = wid & 1;
    const int lrow = lane & 15;
    const int lk8 = (lane >> 4) * 8;
    constexpr int FM = BMt / 32, FN = BNt / 32;

    f32x4 acc[FM][FN] = {};

    for (int k0 = 0; k0 < K; k0 += 32) {
        // ---- stage A [BMt][32] f32 -> split hi/lo LDS ----
#pragma unroll
        for (int c = 0; c < BMt / 32; c++) {
            const int s = tid + c * 256;       // BMt*8 float4 slots
            const int row = s >> 3, k4 = (s & 7) * 4;
            const int gk = k0 + k4;            // mult of 4; never straddles DP_
            const float* ap;
            if (CONCAT) {
                ap = (gk < DP_) ? A0 + (size_t)(rowBase + row) * DP_ + gk
                                : A1 + (size_t)(rowBase + row) * DA_ + (gk - DP_);
            } else {
                ap = A0 + (size_t)(rowBase + row) * K + gk;
            }
            const float4 v = *(const float4*)ap;
            const float xs[4] = {v.x, v.y, v.z, v.w};
            ushort_t h[4], l[4];
#pragma unroll
            for (int j = 0; j < 4; j++) {
                h[j] = f2bs(xs[j]);
                l[j] = f2bs(xs[j] - bs2f(h[j]));
            }
            *(uint2*)&AsH[row * SA + k4] = *(const uint2*)h;
            *(uint2*)&AsL[row * SA + k4] = *(const uint2*)l;
        }
        // ---- stage B [BNt][32] from bf16 planes ----
#pragma unroll
        for (int c = 0; c < BNt / 64; c++) {
            const int chunk = tid + c * 256;   // BNt*4 uint4 slots
            const int row = chunk >> 2, k8 = (chunk & 3) * 8;
            const size_t off = (size_t)(colBase + row) * K + k0 + k8;
            *(uint4*)&BsH[row * SA + k8] = *(const uint4*)(BTH + off);
            *(uint4*)&BsL[row * SA + k8] = *(const uint4*)(BTL + off);
        }
        __syncthreads();

        bf16x8 ah[FM], al[FM], bh[FN], bl[FN];
#pragma unroll
        for (int m = 0; m < FM; m++) {
            const int r = (wr * (BMt / 2) + m * 16 + lrow) * SA + lk8;
            ah[m] = *(const bf16x8*)&AsH[r];
            al[m] = *(const bf16x8*)&AsL[r];
        }
#pragma unroll
        for (int n = 0; n < FN; n++) {
            const int r = (wc * (BNt / 2) + n * 16 + lrow) * SA + lk8;
            bh[n] = *(const bf16x8*)&BsH[r];
            bl[n] = *(const bf16x8*)&BsL[r];
        }
#pragma unroll
        for (int m = 0; m < FM; m++)
#pragma unroll
            for (int n = 0; n < FN; n++) {
                acc[m][n] = __builtin_amdgcn_mfma_f32_16x16x32_bf16(
                    ah[m], bh[n], acc[m][n], 0, 0, 0);
                acc[m][n] = __builtin_amdgcn_mfma_f32_16x16x32_bf16(
                    ah[m], bl[n], acc[m][n], 0, 0, 0);
                acc[m][n] = __builtin_amdgcn_mfma_f32_16x16x32_bf16(
                    al[m], bh[n], acc[m][n], 0, 0, 0);
            }
        __syncthreads();
    }

    // epilogue: C/D layout col=lane&15, row=(lane>>4)*4+reg
#pragma unroll
    for (int n = 0; n < FN; n++) {
        const int gc = colBase + wc * (BNt / 2) + n * 16 + lrow;
        const float bv = bias[gc];
#pragma unroll
        for (int m = 0; m < FM; m++) {
            const int gr0 = rowBase + wr * (BMt / 2) + m * 16 + (lane >> 4) * 4;
#pragma unroll
            for (int r = 0; r < 4; r++) {
                float v = acc[m][n][r] + bv;
                if (RELU) v = v > 0.f ? v : 0.f;
                Cout[(size_t)(gr0 + r) * N + gc] = v;
            }
        }
    }
}

// ================= MODE 0 (bf16 storage) path — unchanged, dormant =========

__global__ __launch_bounds__(256) void transpose_bf16(
    const int* __restrict__ flag,
    const ushort_t* __restrict__ src, ushort_t* __restrict__ dst,
    int R, int C)
{
    if (*flag != 0) return;
    __shared__ ushort_t tile[32][33];
    const int nbx = C / 32;
    const int bx = blockIdx.x % nbx;
    const int by = blockIdx.x / nbx;
    const int tx = threadIdx.x % 32, ty = threadIdx.x / 32;
    const int c0 = bx * 32, r0 = by * 32;
#pragma unroll
    for (int i = ty; i < 32; i += 8)
        tile[i][tx] = src[(size_t)(r0 + i) * C + c0 + tx];
    __syncthreads();
#pragma unroll
    for (int i = ty; i < 32; i += 8)
        dst[(size_t)(c0 + i) * R + r0 + tx] = tile[tx][i];
}

template<int BMt, int BNt, int CONCAT, int RELU, int OUTF32>
__global__ __launch_bounds__(256) void gemm_mfma(
    const int* __restrict__ flag,
    const ushort_t* __restrict__ A0,
    const ushort_t* __restrict__ A1,
    const ushort_t* __restrict__ BT,
    const ushort_t* __restrict__ bias,
    void* __restrict__ Cout,
    int N, int K)
{
    if (*flag != 0) return;
    constexpr int SA = 40;
    __shared__ ushort_t As[BMt * SA];
    __shared__ ushort_t Bs[BNt * SA];
    const int tid = threadIdx.x;
    const int nbx = N / BNt;
    const int colBase = (blockIdx.x % nbx) * BNt;
    const int rowBase = (blockIdx.x / nbx) * BMt;
    const int wid = tid >> 6, lane = tid & 63;
    const int wr = wid >> 1, wc = wid & 1;
    const int lrow = lane & 15;
    const int lk8 = (lane >> 4) * 8;
    constexpr int FM = BMt / 32, FN = BNt / 32;

    f32x4 acc[FM][FN] = {};

    for (int k0 = 0; k0 < K; k0 += 32) {
#pragma unroll
        for (int c = 0; c < BMt / 64; c++) {
            const int chunk = tid + c * 256;
            const int row = chunk >> 2, k8 = (chunk & 3) * 8;
            const int gk = k0 + k8;
            const ushort_t* ap;
            if (CONCAT) {
                ap = (gk < DP_) ? A0 + (size_t)(rowBase + row) * DP_ + gk
                                : A1 + (size_t)(rowBase + row) * DA_ + (gk - DP_);
            } else {
                ap = A0 + (size_t)(rowBase + row) * K + gk;
            }
            *(uint4*)&As[row * SA + k8] = *(const uint4*)ap;
        }
#pragma unroll
        for (int c = 0; c < BNt / 64; c++) {
            const int chunk = tid + c * 256;
            const int row = chunk >> 2, k8 = (chunk & 3) * 8;
            *(uint4*)&Bs[row * SA + k8] =
                *(const uint4*)(BT + (size_t)(colBase + row) * K + k0 + k8);
        }
        __syncthreads();

        bf16x8 af[FM], bfr[FN];
#pragma unroll
        for (int m = 0; m < FM; m++)
            af[m] = *(const bf16x8*)&As[(wr * (BMt / 2) + m * 16 + lrow) * SA + lk8];
#pragma unroll
        for (int n = 0; n < FN; n++)
            bfr[n] = *(const bf16x8*)&Bs[(wc * (BNt / 2) + n * 16 + lrow) * SA + lk8];
#pragma unroll
        for (int m = 0; m < FM; m++)
#pragma unroll
            for (int n = 0; n < FN; n++)
                acc[m][n] = __builtin_amdgcn_mfma_f32_16x16x32_bf16(
                    af[m], bfr[n], acc[m][n], 0, 0, 0);
        __syncthreads();
    }

#pragma unroll
    for (int n = 0; n < FN; n++) {
        const int gc = colBase + wc * (BNt / 2) + n * 16 + lrow;
        const float bv = bs2f(bias[gc]);
#pragma unroll
        for (int m = 0; m < FM; m++) {
            const int gr0 = rowBase + wr * (BMt / 2) + m * 16 + (lane >> 4) * 4;
#pragma unroll
            for (int r = 0; r < 4; r++) {
                float v = acc[m][n][r] + bv;
                if (RELU) v = v > 0.f ? v : 0.f;
                if (OUTF32)
                    ((float*)Cout)[(size_t)(gr0 + r) * N + gc] = v;
                else
                    ((__hip_bfloat16*)Cout)[(size_t)(gr0 + r) * N + gc] = __float2bfloat16(v);
            }
        }
    }
}

// Legacy scalar GEMMs (MODE 0 ws-fallback only)
#define BM 64
#define BN 64
#define BK 16

template<typename T, int MODE>
__global__ __launch_bounds__(256) void gemm_bias(
    const int* __restrict__ flag,
    const T* __restrict__ A,
    const T* __restrict__ Bm,
    const T* __restrict__ bias,
    float* __restrict__ C, int M, int N, int K)
{
    if (*flag != MODE) return;
    __shared__ float As[BK][BM + 1];
    __shared__ float Bs[BK][BN + 1];
    const int tid = threadIdx.x;
    const int nbx = N / BN;
    const int bx = blockIdx.x % nbx;
    const int by = blockIdx.x / nbx;
    const int rowBase = by * BM, colBase = bx * BN;
    const int ty = tid / 16, tx = tid % 16;
    float acc[4][4] = {};

    for (int k0 = 0; k0 < K; k0 += BK) {
        {
            const int am = tid >> 2, ak = (tid & 3) * 4;
            const T* ap = A + (size_t)(rowBase + am) * K + k0 + ak;
#pragma unroll
            for (int j = 0; j < 4; j++) As[ak + j][am] = toF(ap[j]);
        }
        {
            const int bk = tid >> 4, bn = (tid & 15) * 4;
            const T* bp2 = Bm + (size_t)(k0 + bk) * N + colBase + bn;
#pragma unroll
            for (int j = 0; j < 4; j++) Bs[bk][bn + j] = toF(bp2[j]);
        }
        __syncthreads();
#pragma unroll
        for (int kk = 0; kk < BK; kk++) {
            float ra[4], rb[4];
#pragma unroll
            for (int i = 0; i < 4; i++) ra[i] = As[kk][ty * 4 + i];
#pragma unroll
            for (int j = 0; j < 4; j++) rb[j] = Bs[kk][tx * 4 + j];
#pragma unroll
            for (int i = 0; i < 4; i++)
#pragma unroll
                for (int j = 0; j < 4; j++) acc[i][j] += ra[i] * rb[j];
        }
        __syncthreads();
    }
#pragma unroll
    for (int i = 0; i < 4; i++) {
        const int r = rowBase + ty * 4 + i;
#pragma unroll
        for (int j = 0; j < 4; j++) {
            const int c = colBase + tx * 4 + j;
            C[(size_t)r * N + c] = acc[i][j] + toF(bias[c]);
        }
    }
}

template<typename T, int MODE>
__global__ __launch_bounds__(256) void gemm_concat_relu(
    const int* __restrict__ flag,
    const T* __restrict__ A0,
    const T* __restrict__ A1,
    const T* __restrict__ Bm,
    const T* __restrict__ bias,
    T* __restrict__ Out, int M)
{
    if (*flag != MODE) return;
    const int N = DO_, K = DP_ + DA_;
    __shared__ float As[BK][BM + 1];
    __shared__ float Bs[BK][BN + 1];
    const int tid = threadIdx.x;
    const int nbx = N / BN;
    const int bx = blockIdx.x % nbx;
    const int by = blockIdx.x / nbx;
    const int rowBase = by * BM, colBase = bx * BN;
    const int ty = tid / 16, tx = tid % 16;
    float acc[4][4] = {};

    for (int k0 = 0; k0 < K; k0 += BK) {
        {
            const int am = tid >> 2, ak = (tid & 3) * 4;
            const int gk = k0 + ak;
            const T* ap = (gk < DP_)
                ? A0 + (size_t)(rowBase + am) * DP_ + gk
                : A1 + (size_t)(rowBase + am) * DA_ + (gk - DP_);
#pragma unroll
            for (int j = 0; j < 4; j++) As[ak + j][am] = toF(ap[j]);
        }
        {
            const int bk = tid >> 4, bn = (tid & 15) * 4;
            const T* bp2 = Bm + (size_t)(k0 + bk) * N + colBase + bn;
#pragma unroll
            for (int j = 0; j < 4; j++) Bs[bk][bn + j] = toF(bp2[j]);
        }
        __syncthreads();
#pragma unroll
        for (int kk = 0; kk < BK; kk++) {
            float ra[4], rb[4];
#pragma unroll
            for (int i = 0; i < 4; i++) ra[i] = As[kk][ty * 4 + i];
#pragma unroll
            for (int j = 0; j < 4; j++) rb[j] = Bs[kk][tx * 4 + j];
#pragma unroll
            for (int i = 0; i < 4; i++)
#pragma unroll
                for (int j = 0; j < 4; j++) acc[i][j] += ra[i] * rb[j];
        }
        __syncthreads();
    }
#pragma unroll
    for (int i = 0; i < 4; i++) {
        const int r = rowBase + ty * 4 + i;
#pragma unroll
        for (int j = 0; j < 4; j++) {
            const int c = colBase + tx * 4 + j;
            float v = acc[i][j] + toF(bias[c]);
            v = v > 0.f ? v : 0.f;
            stT(&Out[(size_t)r * N + c], v);
        }
    }
}

// ---------------- fast tanh ----------------
__device__ __forceinline__ float tanh_fast(float x) {
    float ax = fminf(fabsf(x), 12.0f);
    float e  = __expf(2.0f * ax);
    float t  = 1.0f - __fdividef(2.0f, e + 1.0f);
    return copysignf(t, x);
}

// ---------------- Fused scores -> masked softmax -> agg. One WG per (b, p).
template<typename T, typename PAT, int MODE>
__global__ __launch_bounds__(256) void attn_fused(
    const int* __restrict__ flag,
    const PAT* __restrict__ pa,            // [B*LP, H]
    const float* __restrict__ an,          // [B*LA, H] f32 (ws)
    const T* __restrict__ answer,          // [B*LA, DA]
    const int* __restrict__ amask,         // [B, LA]
    const T* __restrict__ ww,              // [H]
    const T* __restrict__ wbp,             // [1]
    T* __restrict__ agg_out)               // [B*LP, DA]
{
    if (*flag != MODE) return;
    __shared__ float s_pa[HH_];
    __shared__ float s_ww[HH_];
    __shared__ float s_sc[LA_];
    __shared__ float s_at[LA_];

    const int bp_idx = blockIdx.x;
    const int b = bp_idx >> 9;
    const int tid = threadIdx.x;

    for (int h = tid; h < HH_; h += 256) {
        s_pa[h] = toF(pa[(size_t)bp_idx * HH_ + h]);
        s_ww[h] = toF(ww[h]);
    }
    __syncthreads();

    const int a = tid >> 3, l = tid & 7;
    const float* anr = an + (size_t)(b * LA_ + a) * HH_;
    float part = 0.f;
#pragma unroll 8
    for (int h = l; h < HH_; h += 8) {
        float v = s_pa[h] + anr[h];
        part += tanh_fast(v) * s_ww[h];
    }
    part += __shfl_down(part, 4, 8);
    part += __shfl_down(part, 2, 8);
    part += __shfl_down(part, 1, 8);
    if (l == 0) {
        float sc = part + toF(wbp[0]);
        if (amask[b * LA_ + a] == 0) sc = -1e8f;
        s_sc[a] = sc;
    }
    __syncthreads();

    if (tid < 32) {
        float s = s_sc[tid];
        float m = s;
        for (int off = 16; off > 0; off >>= 1) m = fmaxf(m, __shfl_xor(m, off, 32));
        float e = __expf(s - m);
        float sum = e;
        for (int off = 16; off > 0; off >>= 1) sum += __shfl_xor(sum, off, 32);
        s_at[tid] = e / sum;
    }
    __syncthreads();

    const T* ansb = answer + (size_t)b * LA_ * DA_;
    for (int d = tid; d < DA_; d += 256) {
        float acc = 0.f;
#pragma unroll
        for (int a2 = 0; a2 < LA_; a2++)
            acc += s_at[a2] * toF(ansb[a2 * DA_ + d]);
        stT(&agg_out[(size_t)bp_idx * DA_ + d], acc);
    }
}

extern "C" void kernel_launch(void* const* d_in, const int* in_sizes, int n_in,
                              void* d_out, int out_size, void* d_ws, size_t ws_size,
                              hipStream_t stream) {
    const int* amask = (const int*)d_in[3];

    const int M1 = B_ * LA_;   // 512
    const int M2 = B_ * LP_;   // 8192

    int* flag = (int*)d_ws;

    detect_mode<<<1, 1024, 0, stream>>>((const unsigned short*)d_in[0], flag);

    // ================= MODE 1 (f32 storage) — LIVE path =================
    // ws layout: [flag 16B][an f32 1MB][WpTH 1MB][WpTL 1MB][WaTH .5][WaTL .5]
    //            [WoTH 3MB][WoTL 3MB]  total 10.03 MB  (< proven 17.8 MB)
    // pa f32 [8192,512] (16 MB) is stashed in d_out's aligned region (32 MB),
    // which is dead until the final GEMM overwrites it (after attn reads pa).
    {
        const float* ppl    = (const float*)d_in[0];
        const float* answer = (const float*)d_in[2];
        const float* Wp     = (const float*)d_in[4];
        const float* bp     = (const float*)d_in[5];
        const float* Wa     = (const float*)d_in[6];
        const float* ba     = (const float*)d_in[7];
        const float* ww     = (const float*)d_in[8];
        const float* wb     = (const float*)d_in[9];
        const float* Wo     = (const float*)d_in[10];
        const float* bo     = (const float*)d_in[11];
        float* aligned_out = (float*)d_out;
        float* agg_out     = aligned_out + (size_t)M2 * DP_;

        char* cur = (char*)d_ws + 16;
        float* an_ws = (float*)cur;        cur += (size_t)M1 * HH_ * 4;
        ushort_t* WpTH = (ushort_t*)cur;   cur += (size_t)HH_ * DP_ * 2;
        ushort_t* WpTL = (ushort_t*)cur;   cur += (size_t)HH_ * DP_ * 2;
        ushort_t* WaTH = (ushort_t*)cur;   cur += (size_t)HH_ * DA_ * 2;
        ushort_t* WaTL = (ushort_t*)cur;   cur += (size_t)HH_ * DA_ * 2;
        ushort_t* WoTH = (ushort_t*)cur;   cur += (size_t)DO_ * (DP_ + DA_) * 2;
        ushort_t* WoTL = (ushort_t*)cur;

        float* pa_stash = aligned_out;     // first 16 MB of aligned region

        transpose_split_f32<<<(HH_ / 32) * (DA_ / 32), 256, 0, stream>>>(
            flag, Wa, WaTH, WaTL, DA_, HH_);
        transpose_split_f32<<<(HH_ / 32) * (DP_ / 32), 256, 0, stream>>>(
            flag, Wp, WpTH, WpTL, DP_, HH_);
        transpose_split_f32<<<(DO_ / 32) * ((DP_ + DA_) / 32), 256, 0, stream>>>(
            flag, Wo, WoTH, WoTL, DP_ + DA_, DO_);

        // an = answer @ Wa + ba   (M=512, N=512, K=512)
        gemm_mfma_split<64, 64, 0, 0><<<(M1 / 64) * (HH_ / 64), 256, 0, stream>>>(
            flag, answer, nullptr, WaTH, WaTL, ba, an_ws, HH_, DA_);
        // pa = ppl @ Wp + bp      (M=8192, N=512, K=1024) -> stash in d_out
        gemm_mfma_split<128, 128, 0, 0><<<(M2 / 128) * (HH_ / 128), 256, 0, stream>>>(
            flag, ppl, nullptr, WpTH, WpTL, bp, pa_stash, HH_, DP_);
        attn_fused<float, float, 1><<<M2, 256, 0, stream>>>(
            flag, pa_stash, an_ws, answer, amask, ww, wb, agg_out);
        // aligned = relu(concat(ppl, agg) @ Wo + bo)  (M=8192, N=1024, K=1536)
        gemm_mfma_split<128, 128, 1, 1><<<(M2 / 128) * (DO_ / 128), 256, 0, stream>>>(
            flag, ppl, agg_out, WoTH, WoTL, bo, aligned_out, DO_, DP_ + DA_);
    }

    // ================= MODE 0 (bf16 storage) — dormant insurance ==========
    {
        const size_t SZ_PA_F32 = (size_t)M2 * HH_ * 4;
        const size_t SZ_PA_B16 = (size_t)M2 * HH_ * 2;
        const size_t SZ_AN_F32 = (size_t)M1 * HH_ * 4;
        const size_t SZ_WT     = ((size_t)HH_ * DP_ + (size_t)HH_ * DA_
                                  + (size_t)DO_ * (DP_ + DA_)) * 2;
        const size_t NEED_A = 16 + SZ_PA_F32 + SZ_AN_F32 + SZ_WT;
        const size_t NEED_B = 16 + SZ_PA_B16 + SZ_AN_F32 + SZ_WT;

        const ushort_t* ppl    = (const ushort_t*)d_in[0];
        const ushort_t* answer = (const ushort_t*)d_in[2];
        const ushort_t* Wp     = (const ushort_t*)d_in[4];
        const ushort_t* bp     = (const ushort_t*)d_in[5];
        const ushort_t* Wa     = (const ushort_t*)d_in[6];
        const ushort_t* ba     = (const ushort_t*)d_in[7];
        const __hip_bfloat16* ww = (const __hip_bfloat16*)d_in[8];
        const __hip_bfloat16* wb = (const __hip_bfloat16*)d_in[9];
        const ushort_t* Wo     = (const ushort_t*)d_in[10];
        const ushort_t* bo     = (const ushort_t*)d_in[11];
        __hip_bfloat16* aligned_out = (__hip_bfloat16*)d_out;
        __hip_bfloat16* agg_out     = aligned_out + (size_t)B_ * LP_ * DP_;

        const bool tierA = (ws_size >= NEED_A);
        const bool tierB = (ws_size >= NEED_B);

        if (tierA || tierB) {
            char* cur = (char*)d_ws + 16;
            void* pa_any = cur;            cur += tierA ? SZ_PA_F32 : SZ_PA_B16;
            float* an_ws = (float*)cur;    cur += SZ_AN_F32;
            ushort_t* WpT = (ushort_t*)cur; cur += (size_t)HH_ * DP_ * 2;
            ushort_t* WaT = (ushort_t*)cur; cur += (size_t)HH_ * DA_ * 2;
            ushort_t* WoT = (ushort_t*)cur;

            transpose_bf16<<<(DA_ / 32) * (HH_ / 32), 256, 0, stream>>>(
                flag, Wa, WaT, DA_, HH_);
            transpose_bf16<<<(DP_ / 32) * (HH_ / 32), 256, 0, stream>>>(
                flag, Wp, WpT, DP_, HH_);
            transpose_bf16<<<((DP_ + DA_) / 32) * (DO_ / 32), 256, 0, stream>>>(
                flag, Wo, WoT, DP_ + DA_, DO_);

            gemm_mfma<64, 64, 0, 0, 1><<<(M1 / 64) * (HH_ / 64), 256, 0, stream>>>(
                flag, answer, nullptr, WaT, ba, an_ws, HH_, DA_);

            if (tierA) {
                gemm_mfma<128, 128, 0, 0, 1><<<(M2 / 128) * (HH_ / 128), 256, 0, stream>>>(
                    flag, ppl, nullptr, WpT, bp, pa_any, HH_, DP_);
                attn_fused<__hip_bfloat16, float, 0><<<M2, 256, 0, stream>>>(
                    flag, (const float*)pa_any, an_ws, (const __hip_bfloat16*)answer,
                    amask, ww, wb, agg_out);
            } else {
                gemm_mfma<128, 128, 0, 0, 0><<<(M2 / 128) * (HH_ / 128), 256, 0, stream>>>(
                    flag, ppl, nullptr, WpT, bp, pa_any, HH_, DP_);
                attn_fused<__hip_bfloat16, __hip_bfloat16, 0><<<M2, 256, 0, stream>>>(
                    flag, (const __hip_bfloat16*)pa_any, an_ws,
                    (const __hip_bfloat16*)answer, amask, ww, wb, agg_out);
            }

            gemm_mfma<128, 128, 1, 1, 0><<<(M2 / 128) * (DO_ / 128), 256, 0, stream>>>(
                flag, ppl, (const ushort_t*)agg_out, WoT, bo, aligned_out,
                DO_, DP_ + DA_);
        } else {
            float* paF = (float*)((char*)d_ws + 16);
            float* anF = paF + (size_t)M2 * HH_;
            gemm_bias<__hip_bfloat16, 0><<<(M1 / BM) * (HH_ / BN), 256, 0, stream>>>(
                flag, (const __hip_bfloat16*)answer, (const __hip_bfloat16*)Wa,
                (const __hip_bfloat16*)ba, anF, M1, HH_, DA_);
            gemm_bias<__hip_bfloat16, 0><<<(M2 / BM) * (HH_ / BN), 256, 0, stream>>>(
                flag, (const __hip_bfloat16*)ppl, (const __hip_bfloat16*)Wp,
                (const __hip_bfloat16*)bp, paF, M2, HH_, DP_);
            attn_fused<__hip_bfloat16, float, 0><<<M2, 256, 0, stream>>>(
                flag, paF, anF, (const __hip_bfloat16*)answer, amask, ww, wb, agg_out);
            gemm_concat_relu<__hip_bfloat16, 0><<<(M2 / BM) * (DO_ / BN), 256, 0, stream>>>(
                flag, (const __hip_bfloat16*)ppl, agg_out, (const __hip_bfloat16*)Wo,
                (const __hip_bfloat16*)bo, aligned_out, M2);
        }
    }
}